// Round 23
// baseline (59.966 us; speedup 1.0000x reference)
//
#include <hip/hip_runtime.h>
#include <hip/hip_cooperative_groups.h>

namespace cg = cooperative_groups;

#define HW 4096

typedef float f32x4 __attribute__((ext_vector_type(4)));
typedef __bf16 bf16x8 __attribute__((ext_vector_type(8)));
typedef short s16x4 __attribute__((ext_vector_type(4)));

union F8 { bf16x8 v; unsigned long long q[2]; unsigned short u[8]; __bf16 h[8]; };

__device__ inline unsigned short f2bf(float f) {
    unsigned int u = __builtin_bit_cast(unsigned int, f);
    u += 0x7fffu + ((u >> 16) & 1u);   // RNE
    return (unsigned short)(u >> 16);
}
__device__ inline float bf2f(unsigned short h) {
    unsigned int u = ((unsigned int)h) << 16;
    return __builtin_bit_cast(float, u);
}
__device__ inline bf16x8 frag_lo(const unsigned short* p) {
    F8 f; f.q[0] = *(const unsigned long long*)p; f.q[1] = 0ull; return f.v;
}
__device__ inline s16x4 frag4s(const unsigned short* p) {
    union { s16x4 v; unsigned long long q; } f;
    f.q = *(const unsigned long long*)p; return f.v;
}

#define MFMA16(a,b,c) __builtin_amdgcn_mfma_f32_16x16x32_bf16(a, b, c, 0, 0, 0)
#define EXP2(x) __builtin_amdgcn_exp2f(x)

// K=16 S-MFMA via builtin if present (r22: passed either way; dual-path kept)
#if defined(__has_builtin)
#if __has_builtin(__builtin_amdgcn_mfma_f32_16x16x16bf16_1k)
#define HAVE_K16 1
__device__ inline f32x4 SMFMA16x16(s16x4 a, s16x4 b, f32x4 c) {
    return __builtin_amdgcn_mfma_f32_16x16x16bf16_1k(a, b, c, 0, 0, 0);
}
#endif
#endif

// ---------------------------------------------------------------------------
// FUSED cooperative kernel. Ledger (r12/r13): warm proj ~2.5us + warm attn
// ~24us vs two-kernel T=33.4 -> ~6us of per-dispatch launch/drain overhead.
// Fusion removes it; grid sync via cg::this_grid().sync() (the SAFE primitive
// — r18's hand-rolled spin barrier deadlocked on co-residency assumptions;
// cooperative launch guarantees co-residency or fails cleanly).
// Grid 256 x 512thr = v15 attn config exactly (1 blk/CU, 8 waves, cap 256).
//   Phase 1: proj, all 80 rows per block for its 64 pixels (1x x reads).
//   Phase 2: r22 attn byte-equivalent (K16 dual-path, VALU psum L,
//            two-phase bf16 slab merge, fused epilogue).
// LDS: proj W (20.8KB) aliases attn slabs (35.8KB) across the grid sync.
// ---------------------------------------------------------------------------
struct ProjSh { float W[80][64]; float B[80]; };                  // 20800 B
struct AttnSh { unsigned short O[4][64][66]; float L[8][64]; };   // 35840 B

__global__ __launch_bounds__(512, 1) void fused_kernel(
    const float* __restrict__ x,
    const float* __restrict__ Wq, const float* __restrict__ bq,
    const float* __restrict__ Wk, const float* __restrict__ bk,
    const float* __restrict__ Wv, const float* __restrict__ bv,
    unsigned short* __restrict__ qpack, unsigned short* __restrict__ kpack,
    unsigned short* __restrict__ vt3,
    const float* __restrict__ gamma, float* __restrict__ out)
{
    __shared__ __align__(16) char shraw[sizeof(AttnSh)];
    ProjSh* shp = (ProjSh*)shraw;
    AttnSh* sha = (AttnSh*)shraw;

    const float A2 = 0.51006977f;          // log2(e)/sqrt(8), folded into q
    const int blk  = blockIdx.x;
    const int slot = blk & 7;              // XCD slot = (b<<1)|(pt&1)
    const int b    = slot >> 1;
    const int pt   = ((blk >> 3) << 1) | (slot & 1);   // 0..63
    const int tid  = threadIdx.x;
    const int w    = tid >> 6;             // 0..7
    const int lane = tid & 63;
    const int g    = lane >> 4;
    const int ln   = lane & 15;

    // ================= Phase 1: projections (1x x traffic) =================
    {
        const int n = pt * 64 + lane;
#pragma unroll
        for (int kk = 0; kk < 3; ++kk) {
            const int idx = tid + kk * 512;            // f32x4 slot 0..1279
            if (idx < 1280) {
                const int r = idx >> 4;
                const int c = (idx & 15) << 2;
                f32x4 val;
                if (r < 8) { val = *(const f32x4*)(Wq + r * 64 + c); val *= A2; }
                else if (r < 16) val = *(const f32x4*)(Wk + (r - 8) * 64 + c);
                else             val = *(const f32x4*)(Wv + (r - 16) * 64 + c);
                *(f32x4*)(&shp->W[r][c]) = val;
            }
        }
        if (tid < 80) {
            shp->B[tid] = (tid < 8) ? bq[tid] * A2
                        : (tid < 16) ? bk[tid - 8] : bv[tid - 16];
        }
        __syncthreads();

        const float* xb = x + (size_t)b * 64 * HW + n;
        float xv[64];
#pragma unroll
        for (int c = 0; c < 64; ++c) xv[c] = xb[c * HW];

        auto rowdot = [&](int row) -> float {
            const float* wr = &shp->W[row][0];
            float a0 = 0.f, a1 = 0.f, a2 = 0.f, a3 = 0.f;
#pragma unroll
            for (int c4 = 0; c4 < 16; ++c4) {
                f32x4 wv = *(const f32x4*)(wr + c4 * 4);
                a0 = fmaf(wv[0], xv[c4*4+0], a0);
                a1 = fmaf(wv[1], xv[c4*4+1], a1);
                a2 = fmaf(wv[2], xv[c4*4+2], a2);
                a3 = fmaf(wv[3], xv[c4*4+3], a3);
            }
            return (a0 + a1) + (a2 + a3) + shp->B[row];
        };

        const int vslot = (((n >> 2) & 3) << 3) + (n & 3) + (((n >> 4) & 1) << 2);
        unsigned short* vB = vt3 + ((size_t)(b * 128 + (n >> 5)) * 64) * 32 + vslot;

        const int r0 = w * 10;
#pragma unroll
        for (int rr = 0; rr < 10; ++rr) {
            const int row = r0 + rr;        // wave-uniform
            float val = rowdot(row);
            if (row < 8) {
                qpack[(size_t)(b * HW + n) * 8 + row] = f2bf(val);
            } else if (row < 16) {
                kpack[(size_t)(b * HW + n) * 8 + (row - 8)] = f2bf(val);
            } else {
                vB[(size_t)(row - 16) * 32] = f2bf(val);
            }
        }
    }

    // ================= grid-wide sync (cooperative) =================
    cg::this_grid().sync();

    // ================= Phase 2: attention + skip (r22 v15) =================
    const int qt = pt;
    const int nb = qt * 64;

#if HAVE_K16
    const s16x4 z4 = {0, 0, 0, 0};
    s16x4 qf[4];
#pragma unroll
    for (int i = 0; i < 4; ++i)
        qf[i] = (g < 2)
              ? frag4s(qpack + (size_t)(b * HW + nb + 16 * i + ln) * 8 + 4 * g)
              : z4;
#else
    F8 zf; zf.q[0] = 0ull; zf.q[1] = 0ull;
    bf16x8 qf[4];
#pragma unroll
    for (int i = 0; i < 4; ++i)
        qf[i] = (g == 0)
              ? frag_lo(qpack + (size_t)(b * HW + nb + 16 * i + ln) * 8)
              : zf.v;
#endif

    f32x4 o[4][4];
    float psum[4];
#pragma unroll
    for (int i = 0; i < 4; ++i) {
#pragma unroll
        for (int j = 0; j < 4; ++j) o[i][j] = (f32x4){0,0,0,0};
        psum[i] = 0.f;
    }

    const int mq = w * 512;                // this wave's m-slice
    const unsigned short* kb = kpack + (size_t)(b * HW + mq + ln) * 8;
    const unsigned short* vwin = vt3 + ((size_t)b * 128 + w * 16) * 2048
                               + ln * 32 + 8 * g;

#pragma unroll 2
    for (int ch = 0; ch < 16; ++ch) {
        const unsigned short* kp = kb + ch * 256;    // 32 K-rows x 8 ushorts
#if HAVE_K16
        s16x4 kf0 = (g < 2) ? frag4s(kp + 4 * g)       : z4;
        s16x4 kf1 = (g < 2) ? frag4s(kp + 128 + 4 * g) : z4;
#else
        bf16x8 kf0 = (g == 0) ? frag_lo(kp)       : zf.v;
        bf16x8 kf1 = (g == 0) ? frag_lo(kp + 128) : zf.v;
#endif
        const unsigned short* vp = vwin + (size_t)ch * 2048;
        bf16x8 vf0 = *(const bf16x8*)(vp);           // c rows ln
        bf16x8 vf1 = *(const bf16x8*)(vp + 512);     // c rows 16+ln
        bf16x8 vf2 = *(const bf16x8*)(vp + 1024);    // c rows 32+ln
        bf16x8 vf3 = *(const bf16x8*)(vp + 1536);    // c rows 48+ln

        const f32x4 z = {0.f, 0.f, 0.f, 0.f};
#pragma unroll
        for (int i = 0; i < 4; ++i) {
#if HAVE_K16
            f32x4 s0 = SMFMA16x16(kf0, qf[i], z);
            f32x4 s1 = SMFMA16x16(kf1, qf[i], z);
#else
            f32x4 s0 = MFMA16(kf0, qf[i], z);
            f32x4 s1 = MFMA16(kf1, qf[i], z);
#endif
            F8 pa;
            float sacc = 0.f;
#pragma unroll
            for (int r = 0; r < 4; ++r) {
                float e0 = EXP2(s0[r]);
                float e1 = EXP2(s1[r]);
                sacc += e0 + e1;
                pa.h[r]     = (__bf16)e0;
                pa.h[r + 4] = (__bf16)e1;
            }
            psum[i] += sacc;
            o[i][0] = MFMA16(pa.v, vf0, o[i][0]);
            o[i][1] = MFMA16(pa.v, vf1, o[i][1]);
            o[i][2] = MFMA16(pa.v, vf2, o[i][2]);
            o[i][3] = MFMA16(pa.v, vf3, o[i][3]);
        }
    }

    // deferred cross-lane L reduce (sum lane bits 4,5)
#pragma unroll
    for (int i = 0; i < 4; ++i) {
        psum[i] += __shfl_xor(psum[i], 16);
        psum[i] += __shfl_xor(psum[i], 32);
    }

    // two-phase slab merge (LDS region reused after the grid sync)
    if (w < 4) {
#pragma unroll
        for (int i = 0; i < 4; ++i)
#pragma unroll
            for (int r = 0; r < 4; ++r)
#pragma unroll
                for (int j = 0; j < 4; ++j)
                    sha->O[w][16 * i + 4 * g + r][16 * j + ln] = f2bf(o[i][j][r]);
    }
    if (lane < 16) {
#pragma unroll
        for (int i = 0; i < 4; ++i)
            sha->L[w][16 * i + ln] = psum[i];
    }
    __syncthreads();
    if (w >= 4) {
        const int s = w - 4;
#pragma unroll
        for (int i = 0; i < 4; ++i)
#pragma unroll
            for (int r = 0; r < 4; ++r)
#pragma unroll
                for (int j = 0; j < 4; ++j) {
                    unsigned short* p = &sha->O[s][16 * i + 4 * g + r][16 * j + ln];
                    *p = f2bf(bf2f(*p) + o[i][j][r]);
                }
    }
    __syncthreads();

    const int q  = tid & 63;               // query row 0..63
    const int cg_ = tid >> 6;              // 0..7
    float L = 0.f;
#pragma unroll
    for (int wv = 0; wv < 8; ++wv) L += sha->L[wv][q];
    const float inv = 1.0f / L;
    const float gm  = gamma[0];
#pragma unroll
    for (int jj = 0; jj < 8; ++jj) {
        const int c = cg_ + 8 * jj;        // 0..63
        float Ov = bf2f(sha->O[0][q][c]) + bf2f(sha->O[1][q][c])
                 + bf2f(sha->O[2][q][c]) + bf2f(sha->O[3][q][c]);
        const size_t idx = (size_t)(b * 64 + c) * HW + nb + q;
        out[idx] = fmaf(gm, Ov * inv, x[idx]);
    }
}

extern "C" void kernel_launch(void* const* d_in, const int* in_sizes, int n_in,
                              void* d_out, int out_size, void* d_ws, size_t ws_size,
                              hipStream_t stream) {
    const float* x  = (const float*)d_in[0];
    const float* Wq = (const float*)d_in[1];
    const float* bq = (const float*)d_in[2];
    const float* Wk = (const float*)d_in[3];
    const float* bk = (const float*)d_in[4];
    const float* Wv = (const float*)d_in[5];
    const float* bv = (const float*)d_in[6];
    const float* gm = (const float*)d_in[7];

    // ws layout: qpack 256KB | kpack 256KB | vt3 2MB  (total 2.5MB)
    unsigned short* qpack = (unsigned short*)d_ws;
    unsigned short* kpack = qpack + 4 * HW * 8;
    unsigned short* vt3   = kpack + 4 * HW * 8;
    float* out = (float*)d_out;

    void* args[] = { (void*)&x, (void*)&Wq, (void*)&bq, (void*)&Wk,
                     (void*)&bk, (void*)&Wv, (void*)&bv, (void*)&qpack,
                     (void*)&kpack, (void*)&vt3, (void*)&gm, (void*)&out };
    hipLaunchCooperativeKernel(fused_kernel, dim3(256), dim3(512),
                               args, 0, stream);
}

// Round 24
// 59.514 us; speedup vs baseline: 1.0076x; 1.0076x over previous
//
#include <hip/hip_runtime.h>

// ============================================================================
// ROUND 24: AMPLIFIED ATTN PROBE. proj + attn are r22-exact (banked best,
// 30.9us); attn repeats its body x3 in-kernel (barrier-separated, unroll 1)
// so the dispatch rises above the ~40us harness fills and surfaces in the
// top-5 WITH counters. A = dur/3. v15 attn has never been profiled (r13
// profiled v7, three generations back). Next round reverts to single-shot
// with the counter-indicated fix per the decision matrix in the journal.
// ============================================================================

#define HW 4096

typedef float f32x4 __attribute__((ext_vector_type(4)));
typedef __bf16 bf16x8 __attribute__((ext_vector_type(8)));
typedef short s16x4 __attribute__((ext_vector_type(4)));

union F8 { bf16x8 v; unsigned long long q[2]; unsigned short u[8]; __bf16 h[8]; };

__device__ inline unsigned short f2bf(float f) {
    unsigned int u = __builtin_bit_cast(unsigned int, f);
    u += 0x7fffu + ((u >> 16) & 1u);   // RNE
    return (unsigned short)(u >> 16);
}
__device__ inline float bf2f(unsigned short h) {
    unsigned int u = ((unsigned int)h) << 16;
    return __builtin_bit_cast(float, u);
}
__device__ inline bf16x8 frag_lo(const unsigned short* p) {
    F8 f; f.q[0] = *(const unsigned long long*)p; f.q[1] = 0ull; return f.v;
}
__device__ inline s16x4 frag4s(const unsigned short* p) {
    union { s16x4 v; unsigned long long q; } f;
    f.q = *(const unsigned long long*)p; return f.v;
}

#define MFMA16(a,b,c) __builtin_amdgcn_mfma_f32_16x16x32_bf16(a, b, c, 0, 0, 0)
#define EXP2(x) __builtin_amdgcn_exp2f(x)

#if defined(__has_builtin)
#if __has_builtin(__builtin_amdgcn_mfma_f32_16x16x16bf16_1k)
#define HAVE_K16 1
__device__ inline f32x4 SMFMA16x16(s16x4 a, s16x4 b, f32x4 c) {
    return __builtin_amdgcn_mfma_f32_16x16x16bf16_1k(a, b, c, 0, 0, 0);
}
#endif
#endif

// ---------------------------------------------------------------------------
// Kernel 1: projections — r22-exact.
// ---------------------------------------------------------------------------
__global__ __launch_bounds__(256, 4) void proj_kernel(
    const float* __restrict__ x,
    const float* __restrict__ Wq, const float* __restrict__ bq,
    const float* __restrict__ Wk, const float* __restrict__ bk,
    const float* __restrict__ Wv, const float* __restrict__ bv,
    unsigned short* __restrict__ qpack, unsigned short* __restrict__ kpack,
    unsigned short* __restrict__ vt3)
{
    const float A2 = 0.51006977f;      // log2(e)/sqrt(8), folded into q
    __shared__ float ldsW[80][64];
    __shared__ float ldsB[80];

    const int blk   = blockIdx.x;
    const int b     = blk >> 8;
    const int rest  = blk & 255;
    const int ntile = rest >> 2;
    const int rg    = rest & 3;
    const int tid   = threadIdx.x;
    const int w     = tid >> 6;
    const int lane  = tid & 63;
    const int n     = ntile * 64 + lane;

#pragma unroll
    for (int kk = 0; kk < 5; ++kk) {
        const int idx = tid + kk * 256;
        const int r   = idx >> 4;
        const int c   = (idx & 15) << 2;
        f32x4 val;
        if (r < 8) { val = *(const f32x4*)(Wq + r * 64 + c); val *= A2; }
        else if (r < 16) val = *(const f32x4*)(Wk + (r - 8) * 64 + c);
        else             val = *(const f32x4*)(Wv + (r - 16) * 64 + c);
        *(f32x4*)(&ldsW[r][c]) = val;
    }
    if (tid < 80) {
        ldsB[tid] = (tid < 8) ? bq[tid] * A2
                  : (tid < 16) ? bk[tid - 8] : bv[tid - 16];
    }
    __syncthreads();

    const float* xb = x + (size_t)b * 64 * HW + n;
    float xv[64];
#pragma unroll
    for (int c = 0; c < 64; ++c) xv[c] = xb[c * HW];

    auto rowdot = [&](int row) -> float {
        const float* wr = &ldsW[row][0];
        float a0 = 0.f, a1 = 0.f, a2 = 0.f, a3 = 0.f;
#pragma unroll
        for (int c4 = 0; c4 < 16; ++c4) {
            f32x4 wv = *(const f32x4*)(wr + c4 * 4);
            a0 = fmaf(wv[0], xv[c4*4+0], a0);
            a1 = fmaf(wv[1], xv[c4*4+1], a1);
            a2 = fmaf(wv[2], xv[c4*4+2], a2);
            a3 = fmaf(wv[3], xv[c4*4+3], a3);
        }
        return (a0 + a1) + (a2 + a3) + ldsB[row];
    };

    const int vslot = (((n >> 2) & 3) << 3) + (n & 3) + (((n >> 4) & 1) << 2);
    unsigned short* vB = vt3 + ((size_t)(b * 128 + (n >> 5)) * 64) * 32 + vslot;

    const int r0 = rg * 20 + w * 5;
#pragma unroll
    for (int rr = 0; rr < 5; ++rr) {
        const int row = r0 + rr;
        float val = rowdot(row);
        if (row < 8) {
            qpack[(size_t)(b * HW + n) * 8 + row] = f2bf(val);
        } else if (row < 16) {
            kpack[(size_t)(b * HW + n) * 8 + (row - 8)] = f2bf(val);
        } else {
            vB[(size_t)(row - 16) * 32] = f2bf(val);
        }
    }
}

// ---------------------------------------------------------------------------
// Kernel 2: attention + skip — r22 v15 inner code, amplified x3 in-kernel.
// ---------------------------------------------------------------------------
__global__ __launch_bounds__(512, 1) void attn_kernel(
    const unsigned short* __restrict__ qpack,
    const unsigned short* __restrict__ kpack,
    const unsigned short* __restrict__ vt3,
    const float* __restrict__ x,
    const float* __restrict__ gamma,
    float* __restrict__ out)
{
    const int blk  = blockIdx.x;
    const int slot = blk & 7;              // XCD slot = (b<<1)|(qt&1)
    const int j32  = blk >> 3;             // 0..31
    const int b    = slot >> 1;
    const int qt   = (j32 << 1) | (slot & 1);  // 0..63
    const int nb   = qt * 64;
    const int tid  = threadIdx.x;
    const int w    = tid >> 6;             // 0..7 = m-slice
    const int lane = tid & 63;
    const int g    = lane >> 4;
    const int ln   = lane & 15;

    __shared__ unsigned short ldsO[4][64][66];   // bf16 partial slabs
    __shared__ float ldsL[8][64];

#if HAVE_K16
    const s16x4 z4 = {0, 0, 0, 0};
    s16x4 qf[4];
#pragma unroll
    for (int i = 0; i < 4; ++i)
        qf[i] = (g < 2)
              ? frag4s(qpack + (size_t)(b * HW + nb + 16 * i + ln) * 8 + 4 * g)
              : z4;
#else
    F8 zf; zf.q[0] = 0ull; zf.q[1] = 0ull;
    bf16x8 qf[4];
#pragma unroll
    for (int i = 0; i < 4; ++i)
        qf[i] = (g == 0)
              ? frag_lo(qpack + (size_t)(b * HW + nb + 16 * i + ln) * 8)
              : zf.v;
#endif

    const int mq = w * 512;                // this wave's m-slice
    const unsigned short* kb = kpack + (size_t)(b * HW + mq + ln) * 8;
    const unsigned short* vwin = vt3 + ((size_t)b * 128 + w * 16) * 2048
                               + ln * 32 + 8 * g;

#pragma unroll 1
    for (int rep = 0; rep < 3; ++rep) {
        __syncthreads();                   // protect ldsO/ldsL across reps

        f32x4 o[4][4];
        float psum[4];
#pragma unroll
        for (int i = 0; i < 4; ++i) {
#pragma unroll
            for (int j = 0; j < 4; ++j) o[i][j] = (f32x4){0,0,0,0};
            psum[i] = 0.f;
        }

#pragma unroll 2
        for (int ch = 0; ch < 16; ++ch) {
            const unsigned short* kp = kb + ch * 256;
#if HAVE_K16
            s16x4 kf0 = (g < 2) ? frag4s(kp + 4 * g)       : z4;
            s16x4 kf1 = (g < 2) ? frag4s(kp + 128 + 4 * g) : z4;
#else
            bf16x8 kf0 = (g == 0) ? frag_lo(kp)       : zf.v;
            bf16x8 kf1 = (g == 0) ? frag_lo(kp + 128) : zf.v;
#endif
            const unsigned short* vp = vwin + (size_t)ch * 2048;
            bf16x8 vf0 = *(const bf16x8*)(vp);
            bf16x8 vf1 = *(const bf16x8*)(vp + 512);
            bf16x8 vf2 = *(const bf16x8*)(vp + 1024);
            bf16x8 vf3 = *(const bf16x8*)(vp + 1536);

            const f32x4 z = {0.f, 0.f, 0.f, 0.f};
#pragma unroll
            for (int i = 0; i < 4; ++i) {
#if HAVE_K16
                f32x4 s0 = SMFMA16x16(kf0, qf[i], z);
                f32x4 s1 = SMFMA16x16(kf1, qf[i], z);
#else
                f32x4 s0 = MFMA16(kf0, qf[i], z);
                f32x4 s1 = MFMA16(kf1, qf[i], z);
#endif
                F8 pa;
                float sacc = 0.f;
#pragma unroll
                for (int r = 0; r < 4; ++r) {
                    float e0 = EXP2(s0[r]);
                    float e1 = EXP2(s1[r]);
                    sacc += e0 + e1;
                    pa.h[r]     = (__bf16)e0;
                    pa.h[r + 4] = (__bf16)e1;
                }
                psum[i] += sacc;
                o[i][0] = MFMA16(pa.v, vf0, o[i][0]);
                o[i][1] = MFMA16(pa.v, vf1, o[i][1]);
                o[i][2] = MFMA16(pa.v, vf2, o[i][2]);
                o[i][3] = MFMA16(pa.v, vf3, o[i][3]);
            }
        }

#pragma unroll
        for (int i = 0; i < 4; ++i) {
            psum[i] += __shfl_xor(psum[i], 16);
            psum[i] += __shfl_xor(psum[i], 32);
        }

        if (w < 4) {
#pragma unroll
            for (int i = 0; i < 4; ++i)
#pragma unroll
                for (int r = 0; r < 4; ++r)
#pragma unroll
                    for (int j = 0; j < 4; ++j)
                        ldsO[w][16 * i + 4 * g + r][16 * j + ln] = f2bf(o[i][j][r]);
        }
        if (lane < 16) {
#pragma unroll
            for (int i = 0; i < 4; ++i)
                ldsL[w][16 * i + ln] = psum[i];
        }
        __syncthreads();
        if (w >= 4) {
            const int s = w - 4;
#pragma unroll
            for (int i = 0; i < 4; ++i)
#pragma unroll
                for (int r = 0; r < 4; ++r)
#pragma unroll
                    for (int j = 0; j < 4; ++j) {
                        unsigned short* p = &ldsO[s][16 * i + 4 * g + r][16 * j + ln];
                        *p = f2bf(bf2f(*p) + o[i][j][r]);
                    }
        }
        __syncthreads();

        const int q  = tid & 63;
        const int cg = tid >> 6;
        float L = 0.f;
#pragma unroll
        for (int wv = 0; wv < 8; ++wv) L += ldsL[wv][q];
        const float inv = 1.0f / L;
        const float gm  = gamma[0];
#pragma unroll
        for (int jj = 0; jj < 8; ++jj) {
            const int c = cg + 8 * jj;
            float Ov = bf2f(ldsO[0][q][c]) + bf2f(ldsO[1][q][c])
                     + bf2f(ldsO[2][q][c]) + bf2f(ldsO[3][q][c]);
            const size_t idx = (size_t)(b * 64 + c) * HW + nb + q;
            out[idx] = fmaf(gm, Ov * inv, x[idx]);
        }
    }
}

extern "C" void kernel_launch(void* const* d_in, const int* in_sizes, int n_in,
                              void* d_out, int out_size, void* d_ws, size_t ws_size,
                              hipStream_t stream) {
    const float* x  = (const float*)d_in[0];
    const float* Wq = (const float*)d_in[1];
    const float* bq = (const float*)d_in[2];
    const float* Wk = (const float*)d_in[3];
    const float* bk = (const float*)d_in[4];
    const float* Wv = (const float*)d_in[5];
    const float* bv = (const float*)d_in[6];
    const float* gm = (const float*)d_in[7];

    // ws layout: qpack 256KB | kpack 256KB | vt3 2MB  (total 2.5MB)
    unsigned short* qpack = (unsigned short*)d_ws;
    unsigned short* kpack = qpack + 4 * HW * 8;
    unsigned short* vt3   = kpack + 4 * HW * 8;
    float* out = (float*)d_out;

    proj_kernel<<<1024, 256, 0, stream>>>(x, Wq, bq, Wk, bk, Wv, bv,
                                          qpack, kpack, vt3);
    attn_kernel<<<256, 512, 0, stream>>>(qpack, kpack, vt3, x, gm, out);
}

// Round 25
// 57.572 us; speedup vs baseline: 1.0416x; 1.0337x over previous
//
#include <hip/hip_runtime.h>

#define HW 4096

typedef float f32x4 __attribute__((ext_vector_type(4)));
typedef __bf16 bf16x8 __attribute__((ext_vector_type(8)));
typedef short s16x4 __attribute__((ext_vector_type(4)));

union F8 { bf16x8 v; unsigned long long q[2]; unsigned short u[8]; __bf16 h[8]; };

__device__ inline unsigned short f2bf(float f) {
    unsigned int u = __builtin_bit_cast(unsigned int, f);
    u += 0x7fffu + ((u >> 16) & 1u);   // RNE
    return (unsigned short)(u >> 16);
}
__device__ inline float bf2f(unsigned short h) {
    unsigned int u = ((unsigned int)h) << 16;
    return __builtin_bit_cast(float, u);
}
__device__ inline bf16x8 frag_lo(const unsigned short* p) {
    F8 f; f.q[0] = *(const unsigned long long*)p; f.q[1] = 0ull; return f.v;
}
__device__ inline s16x4 frag4s(const unsigned short* p) {
    union { s16x4 v; unsigned long long q; } f;
    f.q = *(const unsigned long long*)p; return f.v;
}

#define MFMA16(a,b,c) __builtin_amdgcn_mfma_f32_16x16x32_bf16(a, b, c, 0, 0, 0)
#define EXP2(x) __builtin_amdgcn_exp2f(x)

#if defined(__has_builtin)
#if __has_builtin(__builtin_amdgcn_mfma_f32_16x16x16bf16_1k)
#define HAVE_K16 1
__device__ inline f32x4 SMFMA16x16(s16x4 a, s16x4 b, f32x4 c) {
    return __builtin_amdgcn_mfma_f32_16x16x16bf16_1k(a, b, c, 0, 0, 0);
}
#endif
#endif

// ---------------------------------------------------------------------------
// Kernel 1: projections — r22-exact (banked).
// ---------------------------------------------------------------------------
__global__ __launch_bounds__(256, 4) void proj_kernel(
    const float* __restrict__ x,
    const float* __restrict__ Wq, const float* __restrict__ bq,
    const float* __restrict__ Wk, const float* __restrict__ bk,
    const float* __restrict__ Wv, const float* __restrict__ bv,
    unsigned short* __restrict__ qpack, unsigned short* __restrict__ kpack,
    unsigned short* __restrict__ vt3)
{
    const float A2 = 0.51006977f;      // log2(e)/sqrt(8), folded into q
    __shared__ float ldsW[80][64];
    __shared__ float ldsB[80];

    const int blk   = blockIdx.x;
    const int b     = blk >> 8;
    const int rest  = blk & 255;
    const int ntile = rest >> 2;
    const int rg    = rest & 3;
    const int tid   = threadIdx.x;
    const int w     = tid >> 6;
    const int lane  = tid & 63;
    const int n     = ntile * 64 + lane;

#pragma unroll
    for (int kk = 0; kk < 5; ++kk) {
        const int idx = tid + kk * 256;
        const int r   = idx >> 4;
        const int c   = (idx & 15) << 2;
        f32x4 val;
        if (r < 8) { val = *(const f32x4*)(Wq + r * 64 + c); val *= A2; }
        else if (r < 16) val = *(const f32x4*)(Wk + (r - 8) * 64 + c);
        else             val = *(const f32x4*)(Wv + (r - 16) * 64 + c);
        *(f32x4*)(&ldsW[r][c]) = val;
    }
    if (tid < 80) {
        ldsB[tid] = (tid < 8) ? bq[tid] * A2
                  : (tid < 16) ? bk[tid - 8] : bv[tid - 16];
    }
    __syncthreads();

    const float* xb = x + (size_t)b * 64 * HW + n;
    float xv[64];
#pragma unroll
    for (int c = 0; c < 64; ++c) xv[c] = xb[c * HW];

    auto rowdot = [&](int row) -> float {
        const float* wr = &ldsW[row][0];
        float a0 = 0.f, a1 = 0.f, a2 = 0.f, a3 = 0.f;
#pragma unroll
        for (int c4 = 0; c4 < 16; ++c4) {
            f32x4 wv = *(const f32x4*)(wr + c4 * 4);
            a0 = fmaf(wv[0], xv[c4*4+0], a0);
            a1 = fmaf(wv[1], xv[c4*4+1], a1);
            a2 = fmaf(wv[2], xv[c4*4+2], a2);
            a3 = fmaf(wv[3], xv[c4*4+3], a3);
        }
        return (a0 + a1) + (a2 + a3) + ldsB[row];
    };

    const int vslot = (((n >> 2) & 3) << 3) + (n & 3) + (((n >> 4) & 1) << 2);
    unsigned short* vB = vt3 + ((size_t)(b * 128 + (n >> 5)) * 64) * 32 + vslot;

    const int r0 = rg * 20 + w * 5;
#pragma unroll
    for (int rr = 0; rr < 5; ++rr) {
        const int row = r0 + rr;
        float val = rowdot(row);
        if (row < 8) {
            qpack[(size_t)(b * HW + n) * 8 + row] = f2bf(val);
        } else if (row < 16) {
            kpack[(size_t)(b * HW + n) * 8 + (row - 8)] = f2bf(val);
        } else {
            vB[(size_t)(row - 16) * 32] = f2bf(val);
        }
    }
}

// ---------------------------------------------------------------------------
// Kernel 2: attention + skip, v16 = v15 at 2x occupancy.
// r24 probe: A=20.7us, VGPR=96, Occ 20.5%, Mfma 25%, VALU 41% -> both pipes
// idle at 2 waves/SIMD = dependency-stall with register headroom. v16:
// 16-wave blocks (1024,1) -> 4 waves/SIMD (cap 128 >= 96, no spill).
// Wave = 64q x 64c x 256m (8 chunks, same 4-chain shape/layouts). Grid 256.
// Merge: 16 partials, two-phase (waves 8-15 RMW slabs 0-7); LDS 71.6KB.
// Differs from failed r16 analog: cap 128 not 64, 1 blk/CU, proven inner.
// ---------------------------------------------------------------------------
__global__ __launch_bounds__(1024, 1) void attn_kernel(
    const unsigned short* __restrict__ qpack,
    const unsigned short* __restrict__ kpack,
    const unsigned short* __restrict__ vt3,
    const float* __restrict__ x,
    const float* __restrict__ gamma,
    float* __restrict__ out)
{
    const int blk  = blockIdx.x;
    const int slot = blk & 7;              // XCD slot = (b<<1)|(qt&1)
    const int j32  = blk >> 3;             // 0..31
    const int b    = slot >> 1;
    const int qt   = (j32 << 1) | (slot & 1);  // 0..63
    const int nb   = qt * 64;
    const int tid  = threadIdx.x;
    const int w    = tid >> 6;             // 0..15 = m-slice
    const int lane = tid & 63;
    const int g    = lane >> 4;
    const int ln   = lane & 15;

    __shared__ unsigned short ldsO[8][64][66];   // bf16 partial slabs
    __shared__ float ldsL[16][64];

#if HAVE_K16
    const s16x4 z4 = {0, 0, 0, 0};
    s16x4 qf[4];
#pragma unroll
    for (int i = 0; i < 4; ++i)
        qf[i] = (g < 2)
              ? frag4s(qpack + (size_t)(b * HW + nb + 16 * i + ln) * 8 + 4 * g)
              : z4;
#else
    F8 zf; zf.q[0] = 0ull; zf.q[1] = 0ull;
    bf16x8 qf[4];
#pragma unroll
    for (int i = 0; i < 4; ++i)
        qf[i] = (g == 0)
              ? frag_lo(qpack + (size_t)(b * HW + nb + 16 * i + ln) * 8)
              : zf.v;
#endif

    f32x4 o[4][4];
    float psum[4];
#pragma unroll
    for (int i = 0; i < 4; ++i) {
#pragma unroll
        for (int j = 0; j < 4; ++j) o[i][j] = (f32x4){0,0,0,0};
        psum[i] = 0.f;
    }

    const int mq = w * 256;                // this wave's m-slice (256 m)
    const unsigned short* kb = kpack + (size_t)(b * HW + mq + ln) * 8;
    const unsigned short* vwin = vt3 + ((size_t)b * 128 + w * 8) * 2048
                               + ln * 32 + 8 * g;

#pragma unroll 2
    for (int ch = 0; ch < 8; ++ch) {
        const unsigned short* kp = kb + ch * 256;    // 32 K-rows x 8 ushorts
#if HAVE_K16
        s16x4 kf0 = (g < 2) ? frag4s(kp + 4 * g)       : z4;
        s16x4 kf1 = (g < 2) ? frag4s(kp + 128 + 4 * g) : z4;
#else
        bf16x8 kf0 = (g == 0) ? frag_lo(kp)       : zf.v;
        bf16x8 kf1 = (g == 0) ? frag_lo(kp + 128) : zf.v;
#endif
        const unsigned short* vp = vwin + (size_t)ch * 2048;
        bf16x8 vf0 = *(const bf16x8*)(vp);           // c rows ln
        bf16x8 vf1 = *(const bf16x8*)(vp + 512);     // c rows 16+ln
        bf16x8 vf2 = *(const bf16x8*)(vp + 1024);    // c rows 32+ln
        bf16x8 vf3 = *(const bf16x8*)(vp + 1536);    // c rows 48+ln

        const f32x4 z = {0.f, 0.f, 0.f, 0.f};
#pragma unroll
        for (int i = 0; i < 4; ++i) {
#if HAVE_K16
            f32x4 s0 = SMFMA16x16(kf0, qf[i], z);
            f32x4 s1 = SMFMA16x16(kf1, qf[i], z);
#else
            f32x4 s0 = MFMA16(kf0, qf[i], z);
            f32x4 s1 = MFMA16(kf1, qf[i], z);
#endif
            F8 pa;
            float sacc = 0.f;
#pragma unroll
            for (int r = 0; r < 4; ++r) {
                float e0 = EXP2(s0[r]);
                float e1 = EXP2(s1[r]);
                sacc += e0 + e1;
                pa.h[r]     = (__bf16)e0;
                pa.h[r + 4] = (__bf16)e1;
            }
            psum[i] += sacc;
            o[i][0] = MFMA16(pa.v, vf0, o[i][0]);
            o[i][1] = MFMA16(pa.v, vf1, o[i][1]);
            o[i][2] = MFMA16(pa.v, vf2, o[i][2]);
            o[i][3] = MFMA16(pa.v, vf3, o[i][3]);
        }
    }

    // deferred cross-lane L reduce (sum lane bits 4,5)
#pragma unroll
    for (int i = 0; i < 4; ++i) {
        psum[i] += __shfl_xor(psum[i], 16);
        psum[i] += __shfl_xor(psum[i], 32);
    }

    // two-phase slab merge: waves 0-7 write slabs 0-7, waves 8-15 RMW
    if (w < 8) {
#pragma unroll
        for (int i = 0; i < 4; ++i)
#pragma unroll
            for (int r = 0; r < 4; ++r)
#pragma unroll
                for (int j = 0; j < 4; ++j)
                    ldsO[w][16 * i + 4 * g + r][16 * j + ln] = f2bf(o[i][j][r]);
    }
    if (lane < 16) {
#pragma unroll
        for (int i = 0; i < 4; ++i)
            ldsL[w][16 * i + ln] = psum[i];
    }
    __syncthreads();
    if (w >= 8) {
        const int s = w - 8;
#pragma unroll
        for (int i = 0; i < 4; ++i)
#pragma unroll
            for (int r = 0; r < 4; ++r)
#pragma unroll
                for (int j = 0; j < 4; ++j) {
                    unsigned short* p = &ldsO[s][16 * i + 4 * g + r][16 * j + ln];
                    *p = f2bf(bf2f(*p) + o[i][j][r]);
                }
    }
    __syncthreads();

    // merge 8 slabs + 16 L rows; fused epilogue out = gamma*(O/L) + x
    const int q  = tid & 63;               // query row 0..63
    const int cg = tid >> 6;               // 0..15
    float L = 0.f;
#pragma unroll
    for (int wv = 0; wv < 16; ++wv) L += ldsL[wv][q];
    const float inv = 1.0f / L;
    const float gm  = gamma[0];
#pragma unroll
    for (int jj = 0; jj < 4; ++jj) {
        const int c = cg + 16 * jj;        // 0..63
        float Ov = 0.f;
#pragma unroll
        for (int s = 0; s < 8; ++s) Ov += bf2f(ldsO[s][q][c]);
        const size_t idx = (size_t)(b * 64 + c) * HW + nb + q;
        out[idx] = fmaf(gm, Ov * inv, x[idx]);
    }
}

extern "C" void kernel_launch(void* const* d_in, const int* in_sizes, int n_in,
                              void* d_out, int out_size, void* d_ws, size_t ws_size,
                              hipStream_t stream) {
    const float* x  = (const float*)d_in[0];
    const float* Wq = (const float*)d_in[1];
    const float* bq = (const float*)d_in[2];
    const float* Wk = (const float*)d_in[3];
    const float* bk = (const float*)d_in[4];
    const float* Wv = (const float*)d_in[5];
    const float* bv = (const float*)d_in[6];
    const float* gm = (const float*)d_in[7];

    // ws layout: qpack 256KB | kpack 256KB | vt3 2MB  (total 2.5MB)
    unsigned short* qpack = (unsigned short*)d_ws;
    unsigned short* kpack = qpack + 4 * HW * 8;
    unsigned short* vt3   = kpack + 4 * HW * 8;
    float* out = (float*)d_out;

    proj_kernel<<<1024, 256, 0, stream>>>(x, Wq, bq, Wk, bk, Wv, bv,
                                          qpack, kpack, vt3);
    attn_kernel<<<256, 1024, 0, stream>>>(qpack, kpack, vt3, x, gm, out);
}

// Round 26
// 30.740 us; speedup vs baseline: 1.9508x; 1.8729x over previous
//
#include <hip/hip_runtime.h>

#define HW 4096

typedef float f32x4 __attribute__((ext_vector_type(4)));
typedef __bf16 bf16x8 __attribute__((ext_vector_type(8)));
typedef short s16x4 __attribute__((ext_vector_type(4)));

union F8 { bf16x8 v; unsigned long long q[2]; unsigned short u[8]; __bf16 h[8]; };

__device__ inline unsigned short f2bf(float f) {
    unsigned int u = __builtin_bit_cast(unsigned int, f);
    u += 0x7fffu + ((u >> 16) & 1u);   // RNE
    return (unsigned short)(u >> 16);
}
__device__ inline float bf2f(unsigned short h) {
    unsigned int u = ((unsigned int)h) << 16;
    return __builtin_bit_cast(float, u);
}
__device__ inline bf16x8 frag_lo(const unsigned short* p) {
    F8 f; f.q[0] = *(const unsigned long long*)p; f.q[1] = 0ull; return f.v;
}
__device__ inline s16x4 frag4s(const unsigned short* p) {
    union { s16x4 v; unsigned long long q; } f;
    f.q = *(const unsigned long long*)p; return f.v;
}

#define MFMA16(a,b,c) __builtin_amdgcn_mfma_f32_16x16x32_bf16(a, b, c, 0, 0, 0)
#define EXP2(x) __builtin_amdgcn_exp2f(x)

// K=16 S-MFMA via builtin if present; fallback = K=32 path. (r22-exact.)
#if defined(__has_builtin)
#if __has_builtin(__builtin_amdgcn_mfma_f32_16x16x16bf16_1k)
#define HAVE_K16 1
__device__ inline f32x4 SMFMA16x16(s16x4 a, s16x4 b, f32x4 c) {
    return __builtin_amdgcn_mfma_f32_16x16x16bf16_1k(a, b, c, 0, 0, 0);
}
#endif
#endif

// ---------------------------------------------------------------------------
// Kernel 1: projections — r22-exact (banked best).
// W staged in LDS (wave-uniform broadcasts); Wq/bq pre-scaled by
// A2 = log2e/sqrt(8); coalesced qpack/kpack [b][n][8]; fragment-major vt3.
// ---------------------------------------------------------------------------
__global__ __launch_bounds__(256, 4) void proj_kernel(
    const float* __restrict__ x,
    const float* __restrict__ Wq, const float* __restrict__ bq,
    const float* __restrict__ Wk, const float* __restrict__ bk,
    const float* __restrict__ Wv, const float* __restrict__ bv,
    unsigned short* __restrict__ qpack, unsigned short* __restrict__ kpack,
    unsigned short* __restrict__ vt3)
{
    const float A2 = 0.51006977f;      // log2(e)/sqrt(8), folded into q
    __shared__ float ldsW[80][64];
    __shared__ float ldsB[80];

    const int blk   = blockIdx.x;
    const int b     = blk >> 8;
    const int rest  = blk & 255;
    const int ntile = rest >> 2;
    const int rg    = rest & 3;
    const int tid   = threadIdx.x;
    const int w     = tid >> 6;
    const int lane  = tid & 63;
    const int n     = ntile * 64 + lane;

#pragma unroll
    for (int kk = 0; kk < 5; ++kk) {
        const int idx = tid + kk * 256;
        const int r   = idx >> 4;
        const int c   = (idx & 15) << 2;
        f32x4 val;
        if (r < 8) { val = *(const f32x4*)(Wq + r * 64 + c); val *= A2; }
        else if (r < 16) val = *(const f32x4*)(Wk + (r - 8) * 64 + c);
        else             val = *(const f32x4*)(Wv + (r - 16) * 64 + c);
        *(f32x4*)(&ldsW[r][c]) = val;
    }
    if (tid < 80) {
        ldsB[tid] = (tid < 8) ? bq[tid] * A2
                  : (tid < 16) ? bk[tid - 8] : bv[tid - 16];
    }
    __syncthreads();

    const float* xb = x + (size_t)b * 64 * HW + n;
    float xv[64];
#pragma unroll
    for (int c = 0; c < 64; ++c) xv[c] = xb[c * HW];

    auto rowdot = [&](int row) -> float {
        const float* wr = &ldsW[row][0];
        float a0 = 0.f, a1 = 0.f, a2 = 0.f, a3 = 0.f;
#pragma unroll
        for (int c4 = 0; c4 < 16; ++c4) {
            f32x4 wv = *(const f32x4*)(wr + c4 * 4);
            a0 = fmaf(wv[0], xv[c4*4+0], a0);
            a1 = fmaf(wv[1], xv[c4*4+1], a1);
            a2 = fmaf(wv[2], xv[c4*4+2], a2);
            a3 = fmaf(wv[3], xv[c4*4+3], a3);
        }
        return (a0 + a1) + (a2 + a3) + ldsB[row];
    };

    const int vslot = (((n >> 2) & 3) << 3) + (n & 3) + (((n >> 4) & 1) << 2);
    unsigned short* vB = vt3 + ((size_t)(b * 128 + (n >> 5)) * 64) * 32 + vslot;

    const int r0 = rg * 20 + w * 5;
#pragma unroll
    for (int rr = 0; rr < 5; ++rr) {
        const int row = r0 + rr;
        float val = rowdot(row);
        if (row < 8) {
            qpack[(size_t)(b * HW + n) * 8 + row] = f2bf(val);
        } else if (row < 16) {
            kpack[(size_t)(b * HW + n) * 8 + (row - 8)] = f2bf(val);
        } else {
            vB[(size_t)(row - 16) * 32] = f2bf(val);
        }
    }
}

// ---------------------------------------------------------------------------
// Kernel 2: attention + skip — r22-exact v15 (banked best, A~20.7us).
// Swapped QK^T (S^T = mfma(K,Q)); C-frag doubles as PV A-frag via the sigma
// slot bijection matching fragment-major vt3; exp2 with scale pre-folded
// into Q (no shift — uniform factor cancels in O/L, exact); VALU psum L
// with deferred shfl reduce; two-phase bf16 slab merge; fused epilogue.
// Wave = 64q x 64c x 512m (4 chains, no dup softmax); (512,1) cap 256,
// VGPR 96, no spill. NOTE (r25): 1024-thr blocks cap VGPR at 64 on this
// toolchain -> 4 waves/SIMD unreachable at 96 VGPR; this 2-wave/SIMD form
// is the measured best.
// ---------------------------------------------------------------------------
__global__ __launch_bounds__(512, 1) void attn_kernel(
    const unsigned short* __restrict__ qpack,
    const unsigned short* __restrict__ kpack,
    const unsigned short* __restrict__ vt3,
    const float* __restrict__ x,
    const float* __restrict__ gamma,
    float* __restrict__ out)
{
    const int blk  = blockIdx.x;
    const int slot = blk & 7;              // XCD slot = (b<<1)|(qt&1)
    const int j32  = blk >> 3;             // 0..31
    const int b    = slot >> 1;
    const int qt   = (j32 << 1) | (slot & 1);  // 0..63
    const int nb   = qt * 64;
    const int tid  = threadIdx.x;
    const int w    = tid >> 6;             // 0..7 = m-slice
    const int lane = tid & 63;
    const int g    = lane >> 4;
    const int ln   = lane & 15;

    __shared__ unsigned short ldsO[4][64][66];   // bf16 partial slabs
    __shared__ float ldsL[8][64];

#if HAVE_K16
    const s16x4 z4 = {0, 0, 0, 0};
    s16x4 qf[4];
#pragma unroll
    for (int i = 0; i < 4; ++i)
        qf[i] = (g < 2)
              ? frag4s(qpack + (size_t)(b * HW + nb + 16 * i + ln) * 8 + 4 * g)
              : z4;
#else
    F8 zf; zf.q[0] = 0ull; zf.q[1] = 0ull;
    bf16x8 qf[4];
#pragma unroll
    for (int i = 0; i < 4; ++i)
        qf[i] = (g == 0)
              ? frag_lo(qpack + (size_t)(b * HW + nb + 16 * i + ln) * 8)
              : zf.v;
#endif

    f32x4 o[4][4];
    float psum[4];
#pragma unroll
    for (int i = 0; i < 4; ++i) {
#pragma unroll
        for (int j = 0; j < 4; ++j) o[i][j] = (f32x4){0,0,0,0};
        psum[i] = 0.f;
    }

    const int mq = w * 512;                // this wave's m-slice
    const unsigned short* kb = kpack + (size_t)(b * HW + mq + ln) * 8;
    const unsigned short* vwin = vt3 + ((size_t)b * 128 + w * 16) * 2048
                               + ln * 32 + 8 * g;

#pragma unroll 2
    for (int ch = 0; ch < 16; ++ch) {
        const unsigned short* kp = kb + ch * 256;    // 32 K-rows x 8 ushorts
#if HAVE_K16
        s16x4 kf0 = (g < 2) ? frag4s(kp + 4 * g)       : z4;
        s16x4 kf1 = (g < 2) ? frag4s(kp + 128 + 4 * g) : z4;
#else
        bf16x8 kf0 = (g == 0) ? frag_lo(kp)       : zf.v;
        bf16x8 kf1 = (g == 0) ? frag_lo(kp + 128) : zf.v;
#endif
        const unsigned short* vp = vwin + (size_t)ch * 2048;
        bf16x8 vf0 = *(const bf16x8*)(vp);           // c rows ln
        bf16x8 vf1 = *(const bf16x8*)(vp + 512);     // c rows 16+ln
        bf16x8 vf2 = *(const bf16x8*)(vp + 1024);    // c rows 32+ln
        bf16x8 vf3 = *(const bf16x8*)(vp + 1536);    // c rows 48+ln

        const f32x4 z = {0.f, 0.f, 0.f, 0.f};
#pragma unroll
        for (int i = 0; i < 4; ++i) {
#if HAVE_K16
            f32x4 s0 = SMFMA16x16(kf0, qf[i], z);
            f32x4 s1 = SMFMA16x16(kf1, qf[i], z);
#else
            f32x4 s0 = MFMA16(kf0, qf[i], z);
            f32x4 s1 = MFMA16(kf1, qf[i], z);
#endif
            F8 pa;
            float sacc = 0.f;
#pragma unroll
            for (int r = 0; r < 4; ++r) {
                float e0 = EXP2(s0[r]);
                float e1 = EXP2(s1[r]);
                sacc += e0 + e1;
                pa.h[r]     = (__bf16)e0;
                pa.h[r + 4] = (__bf16)e1;
            }
            psum[i] += sacc;
            o[i][0] = MFMA16(pa.v, vf0, o[i][0]);
            o[i][1] = MFMA16(pa.v, vf1, o[i][1]);
            o[i][2] = MFMA16(pa.v, vf2, o[i][2]);
            o[i][3] = MFMA16(pa.v, vf3, o[i][3]);
        }
    }

    // deferred cross-lane L reduce (sum lane bits 4,5)
#pragma unroll
    for (int i = 0; i < 4; ++i) {
        psum[i] += __shfl_xor(psum[i], 16);
        psum[i] += __shfl_xor(psum[i], 32);
    }

    // two-phase slab merge
    if (w < 4) {
#pragma unroll
        for (int i = 0; i < 4; ++i)
#pragma unroll
            for (int r = 0; r < 4; ++r)
#pragma unroll
                for (int j = 0; j < 4; ++j)
                    ldsO[w][16 * i + 4 * g + r][16 * j + ln] = f2bf(o[i][j][r]);
    }
    if (lane < 16) {
#pragma unroll
        for (int i = 0; i < 4; ++i)
            ldsL[w][16 * i + ln] = psum[i];
    }
    __syncthreads();
    if (w >= 4) {
        const int s = w - 4;
#pragma unroll
        for (int i = 0; i < 4; ++i)
#pragma unroll
            for (int r = 0; r < 4; ++r)
#pragma unroll
                for (int j = 0; j < 4; ++j) {
                    unsigned short* p = &ldsO[s][16 * i + 4 * g + r][16 * j + ln];
                    *p = f2bf(bf2f(*p) + o[i][j][r]);
                }
    }
    __syncthreads();

    const int q  = tid & 63;               // query row 0..63
    const int cg = tid >> 6;               // 0..7
    float L = 0.f;
#pragma unroll
    for (int wv = 0; wv < 8; ++wv) L += ldsL[wv][q];
    const float inv = 1.0f / L;
    const float gm  = gamma[0];
#pragma unroll
    for (int jj = 0; jj < 8; ++jj) {
        const int c = cg + 8 * jj;         // 0..63
        float Ov = bf2f(ldsO[0][q][c]) + bf2f(ldsO[1][q][c])
                 + bf2f(ldsO[2][q][c]) + bf2f(ldsO[3][q][c]);
        const size_t idx = (size_t)(b * 64 + c) * HW + nb + q;
        out[idx] = fmaf(gm, Ov * inv, x[idx]);
    }
}

extern "C" void kernel_launch(void* const* d_in, const int* in_sizes, int n_in,
                              void* d_out, int out_size, void* d_ws, size_t ws_size,
                              hipStream_t stream) {
    const float* x  = (const float*)d_in[0];
    const float* Wq = (const float*)d_in[1];
    const float* bq = (const float*)d_in[2];
    const float* Wk = (const float*)d_in[3];
    const float* bk = (const float*)d_in[4];
    const float* Wv = (const float*)d_in[5];
    const float* bv = (const float*)d_in[6];
    const float* gm = (const float*)d_in[7];

    // ws layout: qpack 256KB | kpack 256KB | vt3 2MB  (total 2.5MB)
    unsigned short* qpack = (unsigned short*)d_ws;
    unsigned short* kpack = qpack + 4 * HW * 8;
    unsigned short* vt3   = kpack + 4 * HW * 8;
    float* out = (float*)d_out;

    proj_kernel<<<1024, 256, 0, stream>>>(x, Wq, bq, Wk, bk, Wv, bv,
                                          qpack, kpack, vt3);
    attn_kernel<<<256, 512, 0, stream>>>(qpack, kpack, vt3, x, gm, out);
}